// Round 4
// baseline (58.102 us; speedup 1.0000x reference)
//
#include <hip/hip_runtime.h>
#include <cstddef>

// cos(k*pi/16) base values (double, folded to f32 at compile time)
#define CD1 0.9807852804032304
#define CD2 0.9238795325112867
#define CD3 0.8314696123025452
#define CD4 0.7071067811865476
#define CD5 0.5555702330196022
#define CD6 0.3826834323650898
#define CD7 0.19509032201612825

// python listing of _Y_TABLE BEFORE the .T, row-major: YLg[r*8+c]
// (so y_tab[u][v] = YLg[v*8+u] * 0.4)
__device__ const int YLg[64] = {
  16,11,10,16,24,40,51,61,
  12,12,14,19,26,58,60,55,
  14,13,16,24,40,57,69,56,
  14,17,22,29,51,87,80,62,
  18,22,37,56,68,109,103,77,
  24,35,55,64,81,104,113,92,
  49,64,78,87,103,121,120,101,
  72,92,95,98,112,100,103,99
};

// LDS map (floats):
//   [0,    2176)  LDS_A: 32 records x 64, record stride 68 (DCT rows, later e-values)
//   [2176, 4352)  LDS_Q: 32 records x 64, record stride 68 (quantized q, for coalesced dump)
//   [4352, 4416)  KQ table     [4416, 4480) KD table
__global__ __launch_bounds__(256) void diffjpeg_kernel(const float* __restrict__ in,
                                                       float* __restrict__ out)
{
    __shared__ float lds[4480];

    // CT[x][u] = cos((2x+1)*u*pi/16); all accesses compile-time after unroll
    const float CT[8][8] = {
      {1.0f,(float)CD1,(float)CD2,(float)CD3,(float)CD4,(float)CD5,(float)CD6,(float)CD7},
      {1.0f,(float)CD3,(float)CD6,(float)(-CD7),(float)(-CD4),(float)(-CD1),(float)(-CD2),(float)(-CD5)},
      {1.0f,(float)CD5,(float)(-CD6),(float)(-CD1),(float)(-CD4),(float)CD7,(float)CD2,(float)CD3},
      {1.0f,(float)CD7,(float)(-CD2),(float)(-CD5),(float)CD4,(float)CD3,(float)(-CD6),(float)(-CD1)},
      {1.0f,(float)(-CD7),(float)(-CD2),(float)CD5,(float)CD4,(float)(-CD3),(float)(-CD6),(float)CD1},
      {1.0f,(float)(-CD5),(float)(-CD6),(float)CD1,(float)(-CD4),(float)(-CD7),(float)CD2,(float)(-CD3)},
      {1.0f,(float)(-CD3),(float)CD6,(float)CD7,(float)(-CD4),(float)CD1,(float)(-CD2),(float)CD5},
      {1.0f,(float)(-CD1),(float)CD2,(float)(-CD3),(float)CD4,(float)(-CD5),(float)CD6,(float)(-CD7)}
    };

    const int tid = threadIdx.x;
    const int wg  = blockIdx.x;
    const int bc  = wg >> 9;            // 512 workgroups per (b,c) image
    const int rem = wg & 511;
    const int bh  = rem >> 2;           // block-row 0..127
    const int bwq = (rem & 3) * 32;     // first block (in W) of this wg's 32
    const int ch  = bc % 3;
    const int bb  = bc / 3;

    const int blk = tid >> 3;   // block 0..31 within wg
    const int p   = tid & 7;    // spatial row x (stages A/D) / freq col v (stages B/C)

    // base of this wg's image chunk: 8 rows x 256 cols
    const size_t ibase = (size_t)bc * 1048576 + (size_t)bh * 8192 + (size_t)bwq * 8;

    // ---- stage A: direct global load of own 32B row + row DCT ----
    // lane (blk,p) reads row p of block blk; per wave: 8 rows x 256B = 32 full lines
    float d1[8];
    {
        const float* src = in + ibase + (size_t)p * 1024 + blk * 8;
        const float4 m0 = *reinterpret_cast<const float4*>(src);
        const float4 m1 = *reinterpret_cast<const float4*>(src + 4);
        float s[8] = {m0.x, m0.y, m0.z, m0.w, m1.x, m1.y, m1.z, m1.w};
#pragma unroll
        for (int y = 0; y < 8; ++y) s[y] = fmaf(s[y], 255.0f, -128.0f);
#pragma unroll
        for (int v = 0; v < 8; ++v) {
            float acc = 0.0f;
#pragma unroll
            for (int y = 0; y < 8; ++y) acc = fmaf(s[y], CT[y][v], acc);
            d1[v] = acc;
        }
    }

    // quant/dequant tables (runtime-v indexed -> LDS, not per-thread arrays)
    if (tid < 64) {
        const int u = tid >> 3, v = tid & 7;
        const double a_u = u ? 1.0 : 0.7071067811865476;
        const double a_v = v ? 1.0 : 0.7071067811865476;
        const double qt  = (double)YLg[v * 8 + u] * 0.4;   // y_tab[u][v]
        const double al  = a_u * a_v;
        lds[4352 + tid] = (float)(al * 0.25 / qt);          // KQ = SCALE/y_tab
        lds[4416 + tid] = (float)(qt * al * 0.25);          // KD = y_tab*alpha*0.25
    }

    // transpose stage-A rows into LDS_A (record layout)
    *reinterpret_cast<float4*>(&lds[blk * 68 + p * 8])     = make_float4(d1[0], d1[1], d1[2], d1[3]);
    *reinterpret_cast<float4*>(&lds[blk * 68 + p * 8 + 4]) = make_float4(d1[4], d1[5], d1[6], d1[7]);
    __syncthreads();   // barrier 1

    // ---- stage B+C: column DCT, quant -> LDS_Q, dequant, column IDCT -> LDS_A ----
    // thread owns column v=p of block blk: read & rewrite only by this thread
    {
        float c0[8];
#pragma unroll
        for (int x = 0; x < 8; ++x) c0[x] = lds[blk * 68 + x * 8 + p];
        float dq[8];
#pragma unroll
        for (int u = 0; u < 8; ++u) {
            float acc = 0.0f;
#pragma unroll
            for (int x = 0; x < 8; ++x) acc = fmaf(CT[x][u], c0[x], acc);
            const float kq = lds[4352 + u * 8 + p];
            const float kd = lds[4416 + u * 8 + p];
            const float xq = acc * kq;
            const float r  = rintf(xq);        // round half-to-even = jnp.round
            const float d  = xq - r;
            const float qv = r + d * d * d;    // diff_round
            lds[2176 + blk * 68 + u * 8 + p] = qv;   // q -> LDS_Q
            dq[u] = qv * kd;                   // dequant*alpha*0.25
        }
        // column IDCT in registers, write e-values back to own column of LDS_A
#pragma unroll
        for (int x = 0; x < 8; ++x) {
            float acc = 0.0f;
#pragma unroll
            for (int u = 0; u < 8; ++u) acc = fmaf(CT[x][u], dq[u], acc);
            lds[blk * 68 + x * 8 + p] = acc;
        }
    }
    __syncthreads();   // barrier 2 (LDS_Q and LDS_A e-values complete)

    // ---- q dump: wg's 32 records = 8KB contiguous, 1KB per wave-instruction ----
    {
        float* qb = out + (size_t)ch * 8388608 + (size_t)bb * 1048576
                        + ((size_t)(bh * 128) + bwq) * 64;
#pragma unroll
        for (int j = 0; j < 2; ++j) {
            const int flat = j * 1024 + tid * 4;
            const int rec = flat >> 6, off = flat & 63;
            const float4 val = *reinterpret_cast<const float4*>(&lds[2176 + rec * 68 + off]);
            *reinterpret_cast<float4*>(qb + flat) = val;
        }
    }

    // ---- stage D: row IDCT + clip, direct global store of own 32B row ----
    {
        const float4 a0 = *reinterpret_cast<const float4*>(&lds[blk * 68 + p * 8]);
        const float4 a1 = *reinterpret_cast<const float4*>(&lds[blk * 68 + p * 8 + 4]);
        const float e[8] = {a0.x, a0.y, a0.z, a0.w, a1.x, a1.y, a1.z, a1.w};
        float orow[8];
#pragma unroll
        for (int y = 0; y < 8; ++y) {
            float acc = 0.0f;
#pragma unroll
            for (int v = 0; v < 8; ++v) acc = fmaf(e[v], CT[y][v], acc);
            acc += 128.0f;
            acc = fminf(fmaxf(acc, 0.0f), 255.0f);
            orow[y] = acc * (1.0f / 255.0f);
        }
        float* rb = out + (size_t)25165824 + ibase + (size_t)p * 1024 + blk * 8;
        *reinterpret_cast<float4*>(rb)     = make_float4(orow[0], orow[1], orow[2], orow[3]);
        *reinterpret_cast<float4*>(rb + 4) = make_float4(orow[4], orow[5], orow[6], orow[7]);
    }
}

extern "C" void kernel_launch(void* const* d_in, const int* in_sizes, int n_in,
                              void* d_out, int out_size, void* d_ws, size_t ws_size,
                              hipStream_t stream) {
    const float* x = (const float*)d_in[0];
    float*       o = (float*)d_out;
    // 393216 8x8-blocks, 8 threads/block, 256-thread workgroups -> 12288 wgs
    diffjpeg_kernel<<<12288, 256, 0, stream>>>(x, o);
}

// Round 5
// 53.140 us; speedup vs baseline: 1.0934x; 1.0934x over previous
//
#include <hip/hip_runtime.h>
#include <cstddef>

// cos(k*pi/16) base values (double, folded to f32 at compile time)
#define CD1 0.9807852804032304
#define CD2 0.9238795325112867
#define CD3 0.8314696123025452
#define CD4 0.7071067811865476
#define CD5 0.5555702330196022
#define CD6 0.3826834323650898
#define CD7 0.19509032201612825

// python listing of _Y_TABLE BEFORE the .T, row-major: YLg[r*8+c]
// (so y_tab[u][v] = YLg[v*8+u] * 0.4)
__device__ const int YLg[64] = {
  16,11,10,16,24,40,51,61,
  12,12,14,19,26,58,60,55,
  14,13,16,24,40,57,69,56,
  14,17,22,29,51,87,80,62,
  18,22,37,56,68,109,103,77,
  24,35,55,64,81,104,113,92,
  49,64,78,87,103,121,120,101,
  72,92,95,98,112,100,103,99
};

// LDS map (floats) — all regions DISJOINT (4 barriers total):
//   [0,    2080)  IMG : 8 rows x 256, row stride 260 (input rows, later rec rows)
//   [2080, 4256)  A   : 32 records x 64, record stride 68 (DCT rows, later e-values)
//   [4256, 6432)  Q   : 32 records x 64, record stride 68 (quantized, for coalesced dump)
//   [6432, 6496)  KQ  table    [6496, 6560) KD table
__global__ __launch_bounds__(256) void diffjpeg_kernel(const float* __restrict__ in,
                                                       float* __restrict__ out)
{
    __shared__ float lds[6560];

    // CT[x][u] = cos((2x+1)*u*pi/16); all accesses compile-time after unroll
    const float CT[8][8] = {
      {1.0f,(float)CD1,(float)CD2,(float)CD3,(float)CD4,(float)CD5,(float)CD6,(float)CD7},
      {1.0f,(float)CD3,(float)CD6,(float)(-CD7),(float)(-CD4),(float)(-CD1),(float)(-CD2),(float)(-CD5)},
      {1.0f,(float)CD5,(float)(-CD6),(float)(-CD1),(float)(-CD4),(float)CD7,(float)CD2,(float)CD3},
      {1.0f,(float)CD7,(float)(-CD2),(float)(-CD5),(float)CD4,(float)CD3,(float)(-CD6),(float)(-CD1)},
      {1.0f,(float)(-CD7),(float)(-CD2),(float)CD5,(float)CD4,(float)(-CD3),(float)(-CD6),(float)CD1},
      {1.0f,(float)(-CD5),(float)(-CD6),(float)CD1,(float)(-CD4),(float)(-CD7),(float)CD2,(float)(-CD3)},
      {1.0f,(float)(-CD3),(float)CD6,(float)CD7,(float)(-CD4),(float)CD1,(float)(-CD2),(float)CD5},
      {1.0f,(float)(-CD1),(float)CD2,(float)(-CD3),(float)CD4,(float)(-CD5),(float)CD6,(float)(-CD7)}
    };

    const int tid = threadIdx.x;
    const int wg  = blockIdx.x;
    const int bc  = wg >> 9;            // 512 workgroups per (b,c) image
    const int rem = wg & 511;
    const int bh  = rem >> 2;           // block-row 0..127
    const int bwq = (rem & 3) * 32;     // first block (in W) of this wg's 32
    const int ch  = bc % 3;
    const int bb  = bc / 3;

    const int blk = tid >> 3;   // block 0..31 within wg
    const int p   = tid & 7;    // spatial row x (stages A/D) / freq col v (stages B/C)

    // base of this wg's image chunk: 8 rows x 256 cols
    const size_t ibase = (size_t)bc * 1048576 + (size_t)bh * 8192 + (size_t)bwq * 8;

    // ---- stage 0: global -> LDS via async direct-to-LDS (each wave-chunk = one
    //      contiguous 1KB image row = wave-uniform LDS base + lane*16B) ----
#pragma unroll
    for (int j = 0; j < 2; ++j) {
        const int flat = j * 1024 + tid * 4;     // float index within 8x256 chunk
        const int r = flat >> 8, c = flat & 255; // r is wave-uniform
        __builtin_amdgcn_global_load_lds(
            (const __attribute__((address_space(1))) void*)(in + ibase + (size_t)r * 1024 + c),
            (__attribute__((address_space(3))) void*)(&lds[r * 260 + c]),
            16, 0, 0);
    }

    // quant/dequant tables (runtime-v indexed -> LDS, not per-thread arrays)
    if (tid < 64) {
        const int u = tid >> 3, v = tid & 7;
        const double a_u = u ? 1.0 : 0.7071067811865476;
        const double a_v = v ? 1.0 : 0.7071067811865476;
        const double qt  = (double)YLg[v * 8 + u] * 0.4;   // y_tab[u][v]
        const double al  = a_u * a_v;
        lds[6432 + tid] = (float)(al * 0.25 / qt);          // KQ = SCALE/y_tab
        lds[6496 + tid] = (float)(qt * al * 0.25);          // KD = y_tab*alpha*0.25
    }
    __syncthreads();   // B1: IMG + tables complete (drains vmcnt+lgkmcnt)

    // ---- stage A: row DCT (read IMG row, write record to A) ----
    {
        const float4 m0 = *reinterpret_cast<const float4*>(&lds[p * 260 + blk * 8]);
        const float4 m1 = *reinterpret_cast<const float4*>(&lds[p * 260 + blk * 8 + 4]);
        float s[8] = {m0.x, m0.y, m0.z, m0.w, m1.x, m1.y, m1.z, m1.w};
        float d1[8];
#pragma unroll
        for (int y = 0; y < 8; ++y) s[y] = fmaf(s[y], 255.0f, -128.0f);
#pragma unroll
        for (int v = 0; v < 8; ++v) {
            float acc = 0.0f;
#pragma unroll
            for (int y = 0; y < 8; ++y) acc = fmaf(s[y], CT[y][v], acc);
            d1[v] = acc;
        }
        *reinterpret_cast<float4*>(&lds[2080 + blk * 68 + p * 8])     = make_float4(d1[0], d1[1], d1[2], d1[3]);
        *reinterpret_cast<float4*>(&lds[2080 + blk * 68 + p * 8 + 4]) = make_float4(d1[4], d1[5], d1[6], d1[7]);
    }
    __syncthreads();   // B2: A complete

    // ---- stage B+C: column DCT + quant -> Q, dequant + column IDCT -> A ----
    // thread owns column v=p of block blk (reads/writes only its own column of A)
    {
        float c0[8];
#pragma unroll
        for (int x = 0; x < 8; ++x) c0[x] = lds[2080 + blk * 68 + x * 8 + p];
        float dq[8];
#pragma unroll
        for (int u = 0; u < 8; ++u) {
            float acc = 0.0f;
#pragma unroll
            for (int x = 0; x < 8; ++x) acc = fmaf(CT[x][u], c0[x], acc);
            const float kq = lds[6432 + u * 8 + p];
            const float kd = lds[6496 + u * 8 + p];
            const float xq = acc * kq;
            const float r  = rintf(xq);        // round half-to-even = jnp.round
            const float d  = xq - r;
            const float qv = r + d * d * d;    // diff_round
            lds[4256 + blk * 68 + u * 8 + p] = qv;   // q -> Q
            dq[u] = qv * kd;                   // dequant*alpha*0.25
        }
#pragma unroll
        for (int x = 0; x < 8; ++x) {
            float acc = 0.0f;
#pragma unroll
            for (int u = 0; u < 8; ++u) acc = fmaf(CT[x][u], dq[u], acc);
            lds[2080 + blk * 68 + x * 8 + p] = acc;  // e-values -> A (own column)
        }
    }
    __syncthreads();   // B3: Q + A(e) complete

    // ---- q dump: wg's 32 records = 8KB contiguous, 1KB per wave-instruction ----
    {
        float* qb = out + (size_t)ch * 8388608 + (size_t)bb * 1048576
                        + ((size_t)(bh * 128) + bwq) * 64;
#pragma unroll
        for (int j = 0; j < 2; ++j) {
            const int flat = j * 1024 + tid * 4;
            const int rec = flat >> 6, off = flat & 63;
            const float4 val = *reinterpret_cast<const float4*>(&lds[4256 + rec * 68 + off]);
            *reinterpret_cast<float4*>(qb + flat) = val;
        }
    }

    // ---- stage D: row IDCT + clip (read A rows, write rec rows into IMG) ----
    {
        const float4 a0 = *reinterpret_cast<const float4*>(&lds[2080 + blk * 68 + p * 8]);
        const float4 a1 = *reinterpret_cast<const float4*>(&lds[2080 + blk * 68 + p * 8 + 4]);
        const float e[8] = {a0.x, a0.y, a0.z, a0.w, a1.x, a1.y, a1.z, a1.w};
        float orow[8];
#pragma unroll
        for (int y = 0; y < 8; ++y) {
            float acc = 0.0f;
#pragma unroll
            for (int v = 0; v < 8; ++v) acc = fmaf(e[v], CT[y][v], acc);
            acc += 128.0f;
            acc = fminf(fmaxf(acc, 0.0f), 255.0f);
            orow[y] = acc * (1.0f / 255.0f);
        }
        *reinterpret_cast<float4*>(&lds[p * 260 + blk * 8])     = make_float4(orow[0], orow[1], orow[2], orow[3]);
        *reinterpret_cast<float4*>(&lds[p * 260 + blk * 8 + 4]) = make_float4(orow[4], orow[5], orow[6], orow[7]);
    }
    __syncthreads();   // B4: IMG (rec) complete

    // ---- rec dump: 8 image rows x 1KB, fully coalesced ----
    {
        float* rb = out + (size_t)25165824 + ibase;
#pragma unroll
        for (int j = 0; j < 2; ++j) {
            const int flat = j * 1024 + tid * 4;
            const int r = flat >> 8, c = flat & 255;
            const float4 val = *reinterpret_cast<const float4*>(&lds[r * 260 + c]);
            *reinterpret_cast<float4*>(rb + (size_t)r * 1024 + c) = val;
        }
    }
}

extern "C" void kernel_launch(void* const* d_in, const int* in_sizes, int n_in,
                              void* d_out, int out_size, void* d_ws, size_t ws_size,
                              hipStream_t stream) {
    const float* x = (const float*)d_in[0];
    float*       o = (float*)d_out;
    // 393216 8x8-blocks, 8 threads/block, 256-thread workgroups -> 12288 wgs
    diffjpeg_kernel<<<12288, 256, 0, stream>>>(x, o);
}

// Round 6
// 49.896 us; speedup vs baseline: 1.1645x; 1.0650x over previous
//
#include <hip/hip_runtime.h>
#include <cstddef>

// cos(k*pi/16) base values (double, folded to f32 at compile time)
#define CD1 0.9807852804032304
#define CD2 0.9238795325112867
#define CD3 0.8314696123025452
#define CD4 0.7071067811865476
#define CD5 0.5555702330196022
#define CD6 0.3826834323650898
#define CD7 0.19509032201612825

typedef float v4f __attribute__((ext_vector_type(4)));

// python listing of _Y_TABLE BEFORE the .T, row-major: YLg[r*8+c]
// (so y_tab[u][v] = YLg[v*8+u] * 0.4)
__device__ const int YLg[64] = {
  16,11,10,16,24,40,51,61,
  12,12,14,19,26,58,60,55,
  14,13,16,24,40,57,69,56,
  14,17,22,29,51,87,80,62,
  18,22,37,56,68,109,103,77,
  24,35,55,64,81,104,113,92,
  49,64,78,87,103,121,120,101,
  72,92,95,98,112,100,103,99
};

// LDS map (floats) — all regions DISJOINT (4 barriers total):
//   [0,    2080)  IMG : 8 rows x 256, row stride 260 (input rows, later rec rows)
//   [2080, 4256)  A   : 32 records x 64, record stride 68 (DCT rows, later e-values)
//   [4256, 6432)  Q   : 32 records x 64, record stride 68 (quantized, for coalesced dump)
//   [6432, 6496)  KQ  table    [6496, 6560) KD table
__global__ __launch_bounds__(256) void diffjpeg_kernel(const float* __restrict__ in,
                                                       float* __restrict__ out)
{
    __shared__ float lds[6560];

    // CT[x][u] = cos((2x+1)*u*pi/16); all accesses compile-time after unroll
    const float CT[8][8] = {
      {1.0f,(float)CD1,(float)CD2,(float)CD3,(float)CD4,(float)CD5,(float)CD6,(float)CD7},
      {1.0f,(float)CD3,(float)CD6,(float)(-CD7),(float)(-CD4),(float)(-CD1),(float)(-CD2),(float)(-CD5)},
      {1.0f,(float)CD5,(float)(-CD6),(float)(-CD1),(float)(-CD4),(float)CD7,(float)CD2,(float)CD3},
      {1.0f,(float)CD7,(float)(-CD2),(float)(-CD5),(float)CD4,(float)CD3,(float)(-CD6),(float)(-CD1)},
      {1.0f,(float)(-CD7),(float)(-CD2),(float)CD5,(float)CD4,(float)(-CD3),(float)(-CD6),(float)CD1},
      {1.0f,(float)(-CD5),(float)(-CD6),(float)CD1,(float)(-CD4),(float)(-CD7),(float)CD2,(float)(-CD3)},
      {1.0f,(float)(-CD3),(float)CD6,(float)CD7,(float)(-CD4),(float)CD1,(float)(-CD2),(float)CD5},
      {1.0f,(float)(-CD1),(float)CD2,(float)(-CD3),(float)CD4,(float)(-CD5),(float)CD6,(float)(-CD7)}
    };

    const int tid = threadIdx.x;
    const int wg  = blockIdx.x;
    const int bc  = wg >> 9;            // 512 workgroups per (b,c) image
    const int rem = wg & 511;
    const int bh  = rem >> 2;           // block-row 0..127
    const int bwq = (rem & 3) * 32;     // first block (in W) of this wg's 32
    const int ch  = bc % 3;
    const int bb  = bc / 3;

    const int blk = tid >> 3;   // block 0..31 within wg
    const int p   = tid & 7;    // spatial row x (stages A/D) / freq col v (stages B/C)

    // base of this wg's image chunk: 8 rows x 256 cols
    const size_t ibase = (size_t)bc * 1048576 + (size_t)bh * 8192 + (size_t)bwq * 8;

    // ---- stage 0: global -> LDS via async direct-to-LDS (each wave-chunk = one
    //      contiguous 1KB image row = wave-uniform LDS base + lane*16B) ----
#pragma unroll
    for (int j = 0; j < 2; ++j) {
        const int flat = j * 1024 + tid * 4;     // float index within 8x256 chunk
        const int r = flat >> 8, c = flat & 255; // r is wave-uniform
        __builtin_amdgcn_global_load_lds(
            (const __attribute__((address_space(1))) void*)(in + ibase + (size_t)r * 1024 + c),
            (__attribute__((address_space(3))) void*)(&lds[r * 260 + c]),
            16, 0, 0);
    }

    // quant/dequant tables (runtime-v indexed -> LDS, not per-thread arrays)
    if (tid < 64) {
        const int u = tid >> 3, v = tid & 7;
        const double a_u = u ? 1.0 : 0.7071067811865476;
        const double a_v = v ? 1.0 : 0.7071067811865476;
        const double qt  = (double)YLg[v * 8 + u] * 0.4;   // y_tab[u][v]
        const double al  = a_u * a_v;
        lds[6432 + tid] = (float)(al * 0.25 / qt);          // KQ = SCALE/y_tab
        lds[6496 + tid] = (float)(qt * al * 0.25);          // KD = y_tab*alpha*0.25
    }
    __syncthreads();   // B1: IMG + tables complete (drains vmcnt+lgkmcnt)

    // ---- stage A: row DCT (read IMG row, write record to A) ----
    {
        const float4 m0 = *reinterpret_cast<const float4*>(&lds[p * 260 + blk * 8]);
        const float4 m1 = *reinterpret_cast<const float4*>(&lds[p * 260 + blk * 8 + 4]);
        float s[8] = {m0.x, m0.y, m0.z, m0.w, m1.x, m1.y, m1.z, m1.w};
        float d1[8];
#pragma unroll
        for (int y = 0; y < 8; ++y) s[y] = fmaf(s[y], 255.0f, -128.0f);
#pragma unroll
        for (int v = 0; v < 8; ++v) {
            float acc = 0.0f;
#pragma unroll
            for (int y = 0; y < 8; ++y) acc = fmaf(s[y], CT[y][v], acc);
            d1[v] = acc;
        }
        *reinterpret_cast<float4*>(&lds[2080 + blk * 68 + p * 8])     = make_float4(d1[0], d1[1], d1[2], d1[3]);
        *reinterpret_cast<float4*>(&lds[2080 + blk * 68 + p * 8 + 4]) = make_float4(d1[4], d1[5], d1[6], d1[7]);
    }
    __syncthreads();   // B2: A complete

    // ---- stage B+C: column DCT + quant -> Q, dequant + column IDCT -> A ----
    // thread owns column v=p of block blk (reads/writes only its own column of A)
    {
        float c0[8];
#pragma unroll
        for (int x = 0; x < 8; ++x) c0[x] = lds[2080 + blk * 68 + x * 8 + p];
        float dq[8];
#pragma unroll
        for (int u = 0; u < 8; ++u) {
            float acc = 0.0f;
#pragma unroll
            for (int x = 0; x < 8; ++x) acc = fmaf(CT[x][u], c0[x], acc);
            const float kq = lds[6432 + u * 8 + p];
            const float kd = lds[6496 + u * 8 + p];
            const float xq = acc * kq;
            const float r  = rintf(xq);        // round half-to-even = jnp.round
            const float d  = xq - r;
            const float qv = r + d * d * d;    // diff_round
            lds[4256 + blk * 68 + u * 8 + p] = qv;   // q -> Q
            dq[u] = qv * kd;                   // dequant*alpha*0.25
        }
#pragma unroll
        for (int x = 0; x < 8; ++x) {
            float acc = 0.0f;
#pragma unroll
            for (int u = 0; u < 8; ++u) acc = fmaf(CT[x][u], dq[u], acc);
            lds[2080 + blk * 68 + x * 8 + p] = acc;  // e-values -> A (own column)
        }
    }
    __syncthreads();   // B3: Q + A(e) complete

    // ---- q dump: 8KB contiguous, 1KB per wave-instruction, NONTEMPORAL ----
    // q/rec are write-once, never re-read: stream around L2/L3 so the input
    // stays L3-resident across replays (fetch side goes to ~0).
    {
        float* qb = out + (size_t)ch * 8388608 + (size_t)bb * 1048576
                        + ((size_t)(bh * 128) + bwq) * 64;
#pragma unroll
        for (int j = 0; j < 2; ++j) {
            const int flat = j * 1024 + tid * 4;
            const int rec = flat >> 6, off = flat & 63;
            const v4f val = *reinterpret_cast<const v4f*>(&lds[4256 + rec * 68 + off]);
            __builtin_nontemporal_store(val, reinterpret_cast<v4f*>(qb + flat));
        }
    }

    // ---- stage D: row IDCT + clip (read A rows, write rec rows into IMG) ----
    {
        const float4 a0 = *reinterpret_cast<const float4*>(&lds[2080 + blk * 68 + p * 8]);
        const float4 a1 = *reinterpret_cast<const float4*>(&lds[2080 + blk * 68 + p * 8 + 4]);
        const float e[8] = {a0.x, a0.y, a0.z, a0.w, a1.x, a1.y, a1.z, a1.w};
        float orow[8];
#pragma unroll
        for (int y = 0; y < 8; ++y) {
            float acc = 0.0f;
#pragma unroll
            for (int v = 0; v < 8; ++v) acc = fmaf(e[v], CT[y][v], acc);
            acc += 128.0f;
            acc = fminf(fmaxf(acc, 0.0f), 255.0f);
            orow[y] = acc * (1.0f / 255.0f);
        }
        *reinterpret_cast<float4*>(&lds[p * 260 + blk * 8])     = make_float4(orow[0], orow[1], orow[2], orow[3]);
        *reinterpret_cast<float4*>(&lds[p * 260 + blk * 8 + 4]) = make_float4(orow[4], orow[5], orow[6], orow[7]);
    }
    __syncthreads();   // B4: IMG (rec) complete

    // ---- rec dump: 8 image rows x 1KB, fully coalesced, NONTEMPORAL ----
    {
        float* rb = out + (size_t)25165824 + ibase;
#pragma unroll
        for (int j = 0; j < 2; ++j) {
            const int flat = j * 1024 + tid * 4;
            const int r = flat >> 8, c = flat & 255;
            const v4f val = *reinterpret_cast<const v4f*>(&lds[r * 260 + c]);
            __builtin_nontemporal_store(val, reinterpret_cast<v4f*>(rb + (size_t)r * 1024 + c));
        }
    }
}

extern "C" void kernel_launch(void* const* d_in, const int* in_sizes, int n_in,
                              void* d_out, int out_size, void* d_ws, size_t ws_size,
                              hipStream_t stream) {
    const float* x = (const float*)d_in[0];
    float*       o = (float*)d_out;
    // 393216 8x8-blocks, 8 threads/block, 256-thread workgroups -> 12288 wgs
    diffjpeg_kernel<<<12288, 256, 0, stream>>>(x, o);
}

// Round 7
// 49.097 us; speedup vs baseline: 1.1834x; 1.0163x over previous
//
#include <hip/hip_runtime.h>
#include <cstddef>

// cos(k*pi/16) base values (double, folded to f32 at compile time)
#define CD1 0.9807852804032304
#define CD2 0.9238795325112867
#define CD3 0.8314696123025452
#define CD4 0.7071067811865476
#define CD5 0.5555702330196022
#define CD6 0.3826834323650898
#define CD7 0.19509032201612825

typedef float v4f __attribute__((ext_vector_type(4)));

// ---- compile-time quant/dequant tables, transposed for per-lane contiguity ----
// kq[p*8+u] = _SCALE[u][p] / y_tab[u][p]   (quantize multiplier)
// kd[p*8+u] = y_tab[u][p] * _ALPHA[u][p] * 0.25  (dequant*alpha*0.25)
// y_tab[u][v] = YL[v*8+u] * 0.4  (YL = python _Y_TABLE listing BEFORE the .T)
struct Tabs { float kq[64]; float kd[64]; };
constexpr Tabs mk_tabs() {
    Tabs t{};
    constexpr int YL[64] = {
      16,11,10,16,24,40,51,61,
      12,12,14,19,26,58,60,55,
      14,13,16,24,40,57,69,56,
      14,17,22,29,51,87,80,62,
      18,22,37,56,68,109,103,77,
      24,35,55,64,81,104,113,92,
      49,64,78,87,103,121,120,101,
      72,92,95,98,112,100,103,99 };
    for (int p = 0; p < 8; ++p)
      for (int u = 0; u < 8; ++u) {
        const double a_u = u ? 1.0 : 0.7071067811865476;
        const double a_p = p ? 1.0 : 0.7071067811865476;
        const double qt  = (double)YL[p * 8 + u] * 0.4;   // y_tab[u][p]
        const double al  = a_u * a_p;
        t.kq[p * 8 + u] = (float)(al * 0.25 / qt);
        t.kd[p * 8 + u] = (float)(qt * al * 0.25);
      }
    return t;
}
__device__ const Tabs TB = mk_tabs();

// LDS per wg (one wave): A [0,544), Q [544,1088), R [1088,1632); record/row stride 68
__global__ __launch_bounds__(64) void diffjpeg_kernel(const float* __restrict__ in,
                                                      float* __restrict__ out)
{
    __shared__ float lds[1632];

    // CT[x][u] = cos((2x+1)*u*pi/16); all accesses compile-time after unroll
    const float CT[8][8] = {
      {1.0f,(float)CD1,(float)CD2,(float)CD3,(float)CD4,(float)CD5,(float)CD6,(float)CD7},
      {1.0f,(float)CD3,(float)CD6,(float)(-CD7),(float)(-CD4),(float)(-CD1),(float)(-CD2),(float)(-CD5)},
      {1.0f,(float)CD5,(float)(-CD6),(float)(-CD1),(float)(-CD4),(float)CD7,(float)CD2,(float)CD3},
      {1.0f,(float)CD7,(float)(-CD2),(float)(-CD5),(float)CD4,(float)CD3,(float)(-CD6),(float)(-CD1)},
      {1.0f,(float)(-CD7),(float)(-CD2),(float)CD5,(float)CD4,(float)(-CD3),(float)(-CD6),(float)CD1},
      {1.0f,(float)(-CD5),(float)(-CD6),(float)CD1,(float)(-CD4),(float)(-CD7),(float)CD2,(float)(-CD3)},
      {1.0f,(float)(-CD3),(float)CD6,(float)CD7,(float)(-CD4),(float)CD1,(float)(-CD2),(float)CD5},
      {1.0f,(float)(-CD1),(float)CD2,(float)(-CD3),(float)CD4,(float)(-CD5),(float)CD6,(float)(-CD7)}
    };

    const int tid = threadIdx.x;           // 0..63, one wave per wg
    const int wg  = blockIdx.x;
    const int bc  = wg >> 11;              // 2048 wgs per (b,c) image
    const int rem = wg & 2047;
    const int bh  = rem >> 4;              // block-row 0..127
    const int wq  = rem & 15;              // which 8-block chunk in W
    const int ch  = bc % 3;
    const int bb  = bc / 3;

    const int blk = tid >> 3;   // block 0..7 within wave
    const int p   = tid & 7;    // spatial row x (A/D) / freq col v (B/C)

    // base of this wave's image chunk: 8 rows x 64 cols
    const size_t ibase = (size_t)bc * 1048576 + (size_t)bh * 8192 + (size_t)wq * 64;

    // ---- per-lane quant constants from global const tables (L1-broadcast) ----
    const v4f kq0 = *reinterpret_cast<const v4f*>(&TB.kq[p * 8]);
    const v4f kq1 = *reinterpret_cast<const v4f*>(&TB.kq[p * 8 + 4]);
    const v4f kd0 = *reinterpret_cast<const v4f*>(&TB.kd[p * 8]);
    const v4f kd1 = *reinterpret_cast<const v4f*>(&TB.kd[p * 8 + 4]);
    const float kq[8] = {kq0.x,kq0.y,kq0.z,kq0.w,kq1.x,kq1.y,kq1.z,kq1.w};
    const float kd[8] = {kd0.x,kd0.y,kd0.z,kd0.w,kd1.x,kd1.y,kd1.z,kd1.w};

    // ---- stage A: direct load own 32B block-row + row DCT -> A (transposed write) ----
    {
        const float* src = in + ibase + (size_t)p * 1024 + blk * 8;
        const float4 m0 = *reinterpret_cast<const float4*>(src);
        const float4 m1 = *reinterpret_cast<const float4*>(src + 4);
        float s[8] = {m0.x, m0.y, m0.z, m0.w, m1.x, m1.y, m1.z, m1.w};
        float d1[8];
#pragma unroll
        for (int y = 0; y < 8; ++y) s[y] = fmaf(s[y], 255.0f, -128.0f);
#pragma unroll
        for (int v = 0; v < 8; ++v) {
            float acc = 0.0f;
#pragma unroll
            for (int y = 0; y < 8; ++y) acc = fmaf(s[y], CT[y][v], acc);
            d1[v] = acc;
        }
        *reinterpret_cast<float4*>(&lds[blk * 68 + p * 8])     = make_float4(d1[0], d1[1], d1[2], d1[3]);
        *reinterpret_cast<float4*>(&lds[blk * 68 + p * 8 + 4]) = make_float4(d1[4], d1[5], d1[6], d1[7]);
    }
    __syncthreads();   // single-wave wg: compiles to the required s_waitcnt only

    // ---- stage B+C: column DCT + quant -> Q, dequant + column IDCT -> A ----
    {
        float c0[8];
#pragma unroll
        for (int x = 0; x < 8; ++x) c0[x] = lds[blk * 68 + x * 8 + p];
        float dq[8];
#pragma unroll
        for (int u = 0; u < 8; ++u) {
            float acc = 0.0f;
#pragma unroll
            for (int x = 0; x < 8; ++x) acc = fmaf(CT[x][u], c0[x], acc);
            const float xq = acc * kq[u];
            const float r  = rintf(xq);        // round half-to-even = jnp.round
            const float d  = xq - r;
            const float qv = r + d * d * d;    // diff_round
            lds[544 + blk * 68 + u * 8 + p] = qv;   // q -> Q (own column)
            dq[u] = qv * kd[u];                // dequant*alpha*0.25
        }
#pragma unroll
        for (int x = 0; x < 8; ++x) {
            float acc = 0.0f;
#pragma unroll
            for (int u = 0; u < 8; ++u) acc = fmaf(CT[x][u], dq[u], acc);
            lds[blk * 68 + x * 8 + p] = acc;   // e-values -> A (own column)
        }
    }
    __syncthreads();

    // ---- q dump: wave's 8 records = 2KB contiguous, 1KB/instr, NONTEMPORAL ----
    {
        float* qb = out + (size_t)ch * 8388608 + (size_t)bb * 1048576
                        + ((size_t)(bh * 128) + wq * 8) * 64;
#pragma unroll
        for (int j = 0; j < 2; ++j) {
            const int flat = j * 256 + tid * 4;
            const int rec = flat >> 6, off = flat & 63;
            const v4f val = *reinterpret_cast<const v4f*>(&lds[544 + rec * 68 + off]);
            __builtin_nontemporal_store(val, reinterpret_cast<v4f*>(qb + flat));
        }
    }

    // ---- stage D: row IDCT + clip -> R (row layout) ----
    {
        const float4 a0 = *reinterpret_cast<const float4*>(&lds[blk * 68 + p * 8]);
        const float4 a1 = *reinterpret_cast<const float4*>(&lds[blk * 68 + p * 8 + 4]);
        const float e[8] = {a0.x, a0.y, a0.z, a0.w, a1.x, a1.y, a1.z, a1.w};
        float orow[8];
#pragma unroll
        for (int y = 0; y < 8; ++y) {
            float acc = 0.0f;
#pragma unroll
            for (int v = 0; v < 8; ++v) acc = fmaf(e[v], CT[y][v], acc);
            acc += 128.0f;
            acc = fminf(fmaxf(acc, 0.0f), 255.0f);
            orow[y] = acc * (1.0f / 255.0f);
        }
        *reinterpret_cast<float4*>(&lds[1088 + p * 68 + blk * 8])     = make_float4(orow[0], orow[1], orow[2], orow[3]);
        *reinterpret_cast<float4*>(&lds[1088 + p * 68 + blk * 8 + 4]) = make_float4(orow[4], orow[5], orow[6], orow[7]);
    }
    __syncthreads();

    // ---- rec dump: 8 rows x 256B, 4 rows per instr, NONTEMPORAL ----
    {
        float* rb = out + (size_t)25165824 + ibase;
#pragma unroll
        for (int j = 0; j < 2; ++j) {
            const int flat = j * 256 + tid * 4;
            const int r = flat >> 6, c = flat & 63;
            const v4f val = *reinterpret_cast<const v4f*>(&lds[1088 + r * 68 + c]);
            __builtin_nontemporal_store(val, reinterpret_cast<v4f*>(rb + (size_t)r * 1024 + c));
        }
    }
}

extern "C" void kernel_launch(void* const* d_in, const int* in_sizes, int n_in,
                              void* d_out, int out_size, void* d_ws, size_t ws_size,
                              hipStream_t stream) {
    const float* x = (const float*)d_in[0];
    float*       o = (float*)d_out;
    // 393216 8x8-blocks, 8 blocks per 64-thread (1-wave) wg -> 49152 wgs
    diffjpeg_kernel<<<49152, 64, 0, stream>>>(x, o);
}